// Round 1
// baseline (97.155 us; speedup 1.0000x reference)
//
#include <hip/hip_runtime.h>

#define NW 14
#define NSTATE 16384   // 2^14
#define NT 1024        // threads per block (16 waves)
#define BATCH 128

struct QConsts {
  unsigned M[NW];   // physical pair mask for layer-1 gate on wire w: M_w = P1(1<<(13-w))
  unsigned S[NW];   // parity mask: parity(q & S_w) = logical bit w of P1^{-1}(q)
  unsigned R[NW];   // parity mask for measurement: logical bit w of P2^{-1}(q)
  unsigned ba[NW];  // lowest set bit of M[w] (pair-representative insertion position)
};

__device__ __forceinline__ float2 cmul(float2 a, float2 b) {
  return make_float2(fmaf(a.x, b.x, -a.y * b.y), fmaf(a.x, b.y, a.y * b.x));
}
__device__ __forceinline__ float2 cmadd(float2 a, float2 b, float2 c) {  // a*b + c
  return make_float2(fmaf(a.x, b.x, fmaf(-a.y, b.y, c.x)),
                     fmaf(a.x, b.y, fmaf(a.y, b.x, c.y)));
}

// Full fused matrix M = RX(ax) * RZ(az) * RY(ay); m = {m00, m01, m10, m11}
__device__ __forceinline__ void make_mat(float ay, float az, float ax_, float2 m[4]) {
  float c, s, ct, st, cr, sr;
  sincosf(0.5f * ay, &s, &c);
  sincosf(0.5f * az, &st, &ct);
  sincosf(0.5f * ax_, &sr, &cr);
  float2 em = make_float2(ct, -st), ep = make_float2(ct, st);
  // RZ*RY rows
  float2 r00 = make_float2(c * em.x, c * em.y);
  float2 r01 = make_float2(-s * em.x, -s * em.y);
  float2 r10 = make_float2(s * ep.x, s * ep.y);
  float2 r11 = make_float2(c * ep.x, c * ep.y);
  float2 isr = make_float2(0.f, -sr);  // -i*sr
  m[0] = cmadd(isr, r10, make_float2(cr * r00.x, cr * r00.y));
  m[1] = cmadd(isr, r11, make_float2(cr * r01.x, cr * r01.y));
  m[2] = cmadd(isr, r00, make_float2(cr * r10.x, cr * r10.y));
  m[3] = cmadd(isr, r01, make_float2(cr * r11.x, cr * r11.y));
}

__global__ __launch_bounds__(NT) void qsim_kernel(const float* __restrict__ x,
                                                  const float* __restrict__ params,
                                                  float* __restrict__ out,
                                                  QConsts cst) {
  __shared__ float2 st[NSTATE];      // 128 KB statevector (physical order)
  __shared__ float2 v0[NW][2];       // layer-0 fused-gate column 0 per wire (per-batch)
  __shared__ float2 g1[NW][4];       // layer-1 fused 2x2 per wire (batch-independent)
  __shared__ float2 Ahi[128];        // product over wires 0..6  (bits 13..7)
  __shared__ float2 Blo[128];        // product over wires 7..13 (bits 6..0)
  __shared__ float red[16 * NW];

  const int b = blockIdx.x;
  const int t = threadIdx.x;

  if (t < NW) {
    float2 m[4];
    // layer 0 with data-encoding folded: RY(p0 + x)
    make_mat(params[t * 3 + 0] + x[b * NW + t], params[t * 3 + 1], params[t * 3 + 2], m);
    v0[t][0] = m[0];
    v0[t][1] = m[2];
    make_mat(params[NW * 3 + t * 3 + 0], params[NW * 3 + t * 3 + 1],
             params[NW * 3 + t * 3 + 2], m);
    g1[t][0] = m[0]; g1[t][1] = m[1]; g1[t][2] = m[2]; g1[t][3] = m[3];
  }
  __syncthreads();

  // prefix-product tables for product-state init
  if (t < 128) {
    float2 pa = make_float2(1.f, 0.f);
#pragma unroll
    for (int w = 0; w < 7; ++w) pa = cmul(pa, v0[w][(t >> (6 - w)) & 1]);
    Ahi[t] = pa;
    float2 pb = make_float2(1.f, 0.f);
#pragma unroll
    for (int w = 7; w < 14; ++w) pb = cmul(pb, v0[w][(t >> (13 - w)) & 1]);
    Blo[t] = pb;
  }
  __syncthreads();

  // init: |psi> = tensor product of layer-0 columns (layer-0 1q block applied to |0..0>)
  for (int q = t; q < NSTATE; q += NT) st[q] = cmul(Ahi[q >> 7], Blo[q & 127]);
  __syncthreads();

  // layer-1 single-qubit gates, with layer-0 CNOT chain virtualized into masks
  for (int w = 0; w < NW; ++w) {
    const unsigned M = cst.M[w];
    const unsigned S = cst.S[w];
    const unsigned low = (1u << cst.ba[w]) - 1u;
    const float2 e00 = g1[w][0], e01 = g1[w][1], e10 = g1[w][2], e11 = g1[w][3];
    for (int i = t; i < NSTATE / 2; i += NT) {
      unsigned q0 = ((i & ~low) << 1) | (i & low);  // bit ba == 0
      unsigned q1 = q0 ^ M;
      float2 a0 = st[q0], a1 = st[q1];
      bool sw = __popc(q0 & S) & 1;  // true => q0 holds the logical-1 amplitude
      float2 m00 = sw ? e11 : e00, m01 = sw ? e10 : e01;
      float2 m10 = sw ? e01 : e10, m11 = sw ? e00 : e11;
      st[q0] = cmadd(m01, a1, cmul(m00, a0));
      st[q1] = cmadd(m11, a1, cmul(m10, a0));
    }
    __syncthreads();
  }

  // measurement: <Z_w> with layer-1 CNOT chain virtualized into parity masks R
  float acc[NW];
#pragma unroll
  for (int w = 0; w < NW; ++w) acc[w] = 0.f;
  for (int q = t; q < NSTATE; q += NT) {
    float2 a = st[q];
    float p = fmaf(a.x, a.x, a.y * a.y);
#pragma unroll
    for (int w = 0; w < NW; ++w) acc[w] += (__popc(q & cst.R[w]) & 1) ? -p : p;
  }
#pragma unroll
  for (int w = 0; w < NW; ++w) {
    float v = acc[w];
#pragma unroll
    for (int off = 32; off > 0; off >>= 1) v += __shfl_down(v, off);
    if ((t & 63) == 0) red[(t >> 6) * NW + w] = v;
  }
  __syncthreads();
  if (t < NW) {
    float ssum = 0.f;
#pragma unroll
    for (int i = 0; i < 16; ++i) ssum += red[i * NW + t];
    out[b * NW + t] = ssum;
  }
}

// ---------------- host-side GF(2) permutation bookkeeping ----------------

static unsigned cnot_p(unsigned j, int c, int t) {
  int pc = 13 - c, pt = 13 - t;
  return j ^ (((j >> pc) & 1u) << pt);
}
// Full CNOT chain as basis-state permutation G with state_after[j] = state_before[G(j)]:
// G = g_first ∘ ... ∘ g_last applied as G(j) = g1(g2(...g14(j)))
static unsigned Gperm(unsigned j) {
  j = cnot_p(j, 13, 0);                            // last gate innermost
  for (int w = 12; w >= 0; --w) j = cnot_p(j, w, w + 1);
  return j;
}

// Given columns col[b] = f(1<<b) of an invertible GF(2) map f, return rows of f^{-1}
// as bitmasks: parity(q & rowsInv[r]) = bit r of f^{-1}(q).
static void rows_of_inverse_cols(const unsigned col[NW], unsigned rowsInv[NW]) {
  unsigned rowM[NW], rowI[NW];
  for (int r = 0; r < NW; ++r) { rowM[r] = 0; rowI[r] = 1u << r; }
  for (int bb = 0; bb < NW; ++bb)
    for (int r = 0; r < NW; ++r) rowM[r] |= ((col[bb] >> r) & 1u) << bb;
  for (int c = 0; c < NW; ++c) {
    int piv = c;
    while (!((rowM[piv] >> c) & 1u)) ++piv;
    unsigned tm = rowM[c]; rowM[c] = rowM[piv]; rowM[piv] = tm;
    unsigned ti = rowI[c]; rowI[c] = rowI[piv]; rowI[piv] = ti;
    for (int r = 0; r < NW; ++r)
      if (r != c && ((rowM[r] >> c) & 1u)) { rowM[r] ^= rowM[c]; rowI[r] ^= rowI[c]; }
  }
  for (int r = 0; r < NW; ++r) rowsInv[r] = rowI[r];
}

extern "C" void kernel_launch(void* const* d_in, const int* in_sizes, int n_in,
                              void* d_out, int out_size, void* d_ws, size_t ws_size,
                              hipStream_t stream) {
  (void)in_sizes; (void)n_in; (void)d_ws; (void)ws_size; (void)out_size;

  QConsts cst;
  unsigned colP1[NW], colP2[NW];
  for (int bb = 0; bb < NW; ++bb) {
    colP1[bb] = Gperm(1u << bb);     // P1 = G (after layer-0 CNOT chain)
    colP2[bb] = Gperm(colP1[bb]);    // P2 = G∘G (after layer-1 CNOT chain)
  }
  unsigned invP1rows[NW], invP2rows[NW];
  rows_of_inverse_cols(colP1, invP1rows);
  rows_of_inverse_cols(colP2, invP2rows);
  for (int w = 0; w < NW; ++w) {
    cst.M[w] = colP1[13 - w];
    cst.S[w] = invP1rows[13 - w];
    cst.R[w] = invP2rows[13 - w];
    cst.ba[w] = (unsigned)__builtin_ctz(cst.M[w]);
  }

  const float* x = (const float*)d_in[0];
  const float* params = (const float*)d_in[1];
  float* out = (float*)d_out;

  qsim_kernel<<<dim3(BATCH), dim3(NT), 0, stream>>>(x, params, out, cst);
}

// Round 2
// 78.600 us; speedup vs baseline: 1.2361x; 1.2361x over previous
//
#include <hip/hip_runtime.h>

#define NW 14
#define NT 1024       // 16 waves
#define BATCH 128

// ---------------- compile-time GF(2) permutation bookkeeping ----------------
// CNOT chain as basis permutation G, state_after[j] = state_before[G(j)].
constexpr unsigned cnot_pc(unsigned j, int c, int t) {
  int pc = 13 - c, pt = 13 - t;
  return j ^ (((j >> pc) & 1u) << pt);
}
constexpr unsigned gperm(unsigned j) {
  j = cnot_pc(j, 13, 0);
  for (int w = 12; w >= 0; --w) j = cnot_pc(j, w, w + 1);
  return j;
}
constexpr unsigned topbit(unsigned x) {
  unsigned h = 1;
  while (x >>= 1) h <<= 1;
  return h;
}

struct CT {
  unsigned M[NW], S[NW], R[NW];
  static constexpr void inv(const unsigned col[NW], unsigned out[NW]) {
    unsigned rm[NW] = {}, ri[NW] = {};
    for (int r = 0; r < NW; ++r) { rm[r] = 0; ri[r] = 1u << r; }
    for (int b = 0; b < NW; ++b)
      for (int r = 0; r < NW; ++r) rm[r] |= ((col[b] >> r) & 1u) << b;
    for (int c = 0; c < NW; ++c) {
      int piv = c;
      while (!((rm[piv] >> c) & 1u)) ++piv;
      unsigned tm = rm[c]; rm[c] = rm[piv]; rm[piv] = tm;
      unsigned ti = ri[c]; ri[c] = ri[piv]; ri[piv] = ti;
      for (int r = 0; r < NW; ++r)
        if (r != c && ((rm[r] >> c) & 1u)) { rm[r] ^= rm[c]; ri[r] ^= ri[c]; }
    }
    for (int r = 0; r < NW; ++r) out[r] = ri[r];
  }
  constexpr CT() : M{}, S{}, R{} {
    unsigned c1[NW] = {}, c2[NW] = {};
    for (int b = 0; b < NW; ++b) { c1[b] = gperm(1u << b); c2[b] = gperm(c1[b]); }
    unsigned i1[NW] = {}, i2[NW] = {};
    inv(c1, i1); inv(c2, i2);
    for (int w = 0; w < NW; ++w) { M[w] = c1[13 - w]; S[w] = i1[13 - w]; R[w] = i2[13 - w]; }
  }
};
static constexpr CT qct{};
// smoke tests against hand derivation (same algorithm as the R1-verified host code)
static_assert(qct.M[0] == 0x3000u && qct.M[12] == 0x3u && qct.M[13] == 0x3001u, "mask check");
static_assert(qct.M[4] == 0x300u, "mask check");

// ---------------- complex helpers ----------------
__device__ __forceinline__ float2 cmul(float2 a, float2 b) {
  return make_float2(fmaf(a.x, b.x, -a.y * b.y), fmaf(a.x, b.y, a.y * b.x));
}
__device__ __forceinline__ float2 cmadd(float2 a, float2 b, float2 c) {  // a*b + c
  return make_float2(fmaf(a.x, b.x, fmaf(-a.y, b.y, c.x)),
                     fmaf(a.x, b.y, fmaf(a.y, b.x, c.y)));
}

// fused M = RX(ax) * RZ(az) * RY(ay)
__device__ __forceinline__ void make_mat(float ay, float az, float ax_, float2 m[4]) {
  float c, s, ct, st, cr, sr;
  sincosf(0.5f * ay, &s, &c);
  sincosf(0.5f * az, &st, &ct);
  sincosf(0.5f * ax_, &sr, &cr);
  float2 em = make_float2(ct, -st), ep = make_float2(ct, st);
  float2 r00 = make_float2(c * em.x, c * em.y);
  float2 r01 = make_float2(-s * em.x, -s * em.y);
  float2 r10 = make_float2(s * ep.x, s * ep.y);
  float2 r11 = make_float2(c * ep.x, c * ep.y);
  float2 isr = make_float2(0.f, -sr);
  m[0] = cmadd(isr, r10, make_float2(cr * r00.x, cr * r00.y));
  m[1] = cmadd(isr, r11, make_float2(cr * r01.x, cr * r01.y));
  m[2] = cmadd(isr, r00, make_float2(cr * r10.x, cr * r10.y));
  m[3] = cmadd(isr, r01, make_float2(cr * r11.x, cr * r11.y));
}

// ---------------- register-resident gate application ----------------
// PH=1 layout: q = wave<<10 | lane<<4 | reg(4b)
// PH=2 layout: q = reg<<10 | (lane>>1)<<5 | wave<<1 | (lane&1)
template <int W, int PH>
__device__ __forceinline__ void apply_gate(float2 (&a)[16], const float2* gm, unsigned qt) {
  constexpr unsigned M = qct.M[W], S = qct.S[W];
  constexpr unsigned RM = (PH == 1) ? (M & 0xFu) : ((M >> 10) & 0xFu);
  constexpr unsigned LM = (PH == 1) ? ((M >> 4) & 0x3Fu)
                                    : ((((M >> 5) & 0x1Fu) << 1) | (M & 1u));
  constexpr unsigned SR = (PH == 1) ? (S & 0xFu) : ((S >> 10) & 0xFu);
  static_assert((PH == 1) ? ((M >> 10) == 0u) : (((M >> 1) & 0xFu) == 0u),
                "gate mask crosses wave domain in this phase");
  float2 e00 = gm[0], e01 = gm[1], e10 = gm[2], e11 = gm[3];
  const bool st_ = __popc(qt & S) & 1;
  // pre-swap by the thread-uniform part of the side bit; per-reg part is compile-time
  float2 f00 = st_ ? e11 : e00;
  float2 f01 = st_ ? e10 : e01;
  float2 f10 = st_ ? e01 : e10;
  float2 f11 = st_ ? e00 : e11;
  if constexpr (RM == 0u) {  // pure lane-exchange gate
#pragma unroll
    for (int r = 0; r < 16; ++r) {
      float2 p;
      p.x = __shfl_xor(a[r].x, (int)LM, 64);
      p.y = __shfl_xor(a[r].y, (int)LM, 64);
      if (__popc((unsigned)r & SR) & 1)
        a[r] = cmadd(f10, p, cmul(f11, a[r]));
      else
        a[r] = cmadd(f01, p, cmul(f00, a[r]));
    }
  } else {
    constexpr unsigned HB = topbit(RM);
#pragma unroll
    for (int r = 0; r < 16; ++r) {
      if (r & (int)HB) continue;  // orbit representative
      const int r2i = r ^ (int)RM;
      float2 A = a[r], B = a[r2i];
      float2 pA, pB;
      if constexpr (LM != 0u) {
        pA.x = __shfl_xor(B.x, (int)LM, 64);
        pA.y = __shfl_xor(B.y, (int)LM, 64);
        pB.x = __shfl_xor(A.x, (int)LM, 64);
        pB.y = __shfl_xor(A.y, (int)LM, 64);
      } else {
        pA = B; pB = A;
      }
      a[r] = (__popc((unsigned)r & SR) & 1) ? cmadd(f10, pA, cmul(f11, A))
                                            : cmadd(f01, pA, cmul(f00, A));
      a[r2i] = (__popc((unsigned)r2i & SR) & 1) ? cmadd(f10, pB, cmul(f11, B))
                                                : cmadd(f01, pB, cmul(f00, B));
    }
  }
}

__global__ __launch_bounds__(NT) void qsim_kernel(const float* __restrict__ x,
                                                  const float* __restrict__ params,
                                                  float* __restrict__ out) {
  __shared__ float2 stx[16384];     // 128 KB exchange buffer (XOR-swizzled)
  __shared__ float2 v0[NW][2];      // layer-0 fused column
  __shared__ float2 g1m[NW][4];     // layer-1 fused 2x2
  __shared__ float2 Ahi[128];       // product over wires 0..6 (q bits 13..7)
  __shared__ float2 Blo[8][17];     // product over wires 7..13, padded rows
  __shared__ float red[16][NW];

  const int b = blockIdx.x;
  const int t = threadIdx.x;
  const unsigned wq = (unsigned)t >> 6, lq = (unsigned)t & 63u;

  if (t < NW) {
    float2 m[4];
    make_mat(params[t * 3 + 0] + x[b * NW + t], params[t * 3 + 1], params[t * 3 + 2], m);
    v0[t][0] = m[0];
    v0[t][1] = m[2];
    make_mat(params[NW * 3 + t * 3 + 0], params[NW * 3 + t * 3 + 1],
             params[NW * 3 + t * 3 + 2], m);
    g1m[t][0] = m[0]; g1m[t][1] = m[1]; g1m[t][2] = m[2]; g1m[t][3] = m[3];
  }
  __syncthreads();

  if (t < 128) {
    float2 pa = make_float2(1.f, 0.f);
#pragma unroll
    for (int w = 0; w < 7; ++w) pa = cmul(pa, v0[w][(t >> (6 - w)) & 1]);
    Ahi[t] = pa;
    float2 pb = make_float2(1.f, 0.f);
#pragma unroll
    for (int w = 7; w < 14; ++w) pb = cmul(pb, v0[w][(t >> (13 - w)) & 1]);
    Blo[t >> 4][t & 15] = pb;
  }
  __syncthreads();

  // ---- init straight into registers: a[r] = Ahi[q>>7] * Blo[q&127] ----
  const unsigned qt1 = (wq << 10) | (lq << 4);
  float2 a[16];
  {
    float2 ahi = Ahi[qt1 >> 7];
#pragma unroll
    for (int r = 0; r < 16; ++r) a[r] = cmul(ahi, Blo[lq & 7][r]);
  }

  // ---- phase-1 gates (masks within reg/lane bits 0..9) ----
  apply_gate<4, 1>(a, g1m[4], qt1);
  apply_gate<5, 1>(a, g1m[5], qt1);
  apply_gate<6, 1>(a, g1m[6], qt1);
  apply_gate<7, 1>(a, g1m[7], qt1);
  apply_gate<8, 1>(a, g1m[8], qt1);
  apply_gate<9, 1>(a, g1m[9], qt1);
  apply_gate<10, 1>(a, g1m[10], qt1);
  apply_gate<11, 1>(a, g1m[11], qt1);
  apply_gate<12, 1>(a, g1m[12], qt1);

  // ---- re-layout exchange through XOR-swizzled LDS ----
  // sidx(q) = q ^ ((q>>5)&31); per-thread the swizzle constant is uniform, so
  // write addrs = (qt1^K) ^ r and read addrs = (qt2^K2) | (r<<10).
  const unsigned bw = qt1 ^ ((qt1 >> 5) & 0x1Fu);
#pragma unroll
  for (int r = 0; r < 16; ++r) stx[bw ^ (unsigned)r] = a[r];
  __syncthreads();
  const unsigned qt2 = ((lq >> 1) << 5) | (wq << 1) | (lq & 1u);
  const unsigned br = qt2 ^ ((qt2 >> 5) & 0x1Fu);
#pragma unroll
  for (int r = 0; r < 16; ++r) a[r] = stx[br | ((unsigned)r << 10)];

  // ---- phase-2 gates (masks within new reg bits q[13:10] + lane bits {q9,q8..q5,q0}) ----
  apply_gate<0, 2>(a, g1m[0], qt2);
  apply_gate<1, 2>(a, g1m[1], qt2);
  apply_gate<2, 2>(a, g1m[2], qt2);
  apply_gate<3, 2>(a, g1m[3], qt2);
  apply_gate<13, 2>(a, g1m[13], qt2);

  // ---- measurement: per-thread WHT over the 4 reg bits, then sign-select ----
  float T[16];
#pragma unroll
  for (int r = 0; r < 16; ++r) T[r] = fmaf(a[r].x, a[r].x, a[r].y * a[r].y);
#pragma unroll
  for (int s = 1; s < 16; s <<= 1) {
#pragma unroll
    for (int r = 0; r < 16; ++r) {
      if (!(r & s)) {
        float u = T[r], v = T[r ^ s];
        T[r] = u + v;
        T[r ^ s] = u - v;
      }
    }
  }

  float acc[NW];
#pragma unroll
  for (int w = 0; w < NW; ++w) {
    const unsigned R = qct.R[w];
    float v = T[(R >> 10) & 15u];
    acc[w] = (__popc(qt2 & R) & 1) ? -v : v;
  }
#pragma unroll
  for (int w = 0; w < NW; ++w) {
#pragma unroll
    for (int off = 32; off; off >>= 1) acc[w] += __shfl_down(acc[w], off, 64);
  }
  if ((t & 63) == 0) {
#pragma unroll
    for (int w = 0; w < NW; ++w) red[wq][w] = acc[w];
  }
  __syncthreads();
  if (t < NW) {
    float s = 0.f;
#pragma unroll
    for (int i = 0; i < 16; ++i) s += red[i][t];
    out[b * NW + t] = s;
  }
}

extern "C" void kernel_launch(void* const* d_in, const int* in_sizes, int n_in,
                              void* d_out, int out_size, void* d_ws, size_t ws_size,
                              hipStream_t stream) {
  (void)in_sizes; (void)n_in; (void)d_ws; (void)ws_size; (void)out_size;
  const float* x = (const float*)d_in[0];
  const float* params = (const float*)d_in[1];
  float* out = (float*)d_out;
  qsim_kernel<<<dim3(BATCH), dim3(NT), 0, stream>>>(x, params, out);
}

// Round 3
// 77.831 us; speedup vs baseline: 1.2483x; 1.0099x over previous
//
#include <hip/hip_runtime.h>

#define NW 14
#define NT 1024       // 16 waves
#define BATCH 128

// ---------------- compile-time GF(2) permutation bookkeeping ----------------
constexpr unsigned cnot_pc(unsigned j, int c, int t) {
  int pc = 13 - c, pt = 13 - t;
  return j ^ (((j >> pc) & 1u) << pt);
}
constexpr unsigned gperm(unsigned j) {
  j = cnot_pc(j, 13, 0);
  for (int w = 12; w >= 0; --w) j = cnot_pc(j, w, w + 1);
  return j;
}
constexpr unsigned topbit(unsigned x) {
  unsigned h = 1;
  while (x >>= 1) h <<= 1;
  return h;
}

struct CT {
  unsigned M[NW], S[NW], R[NW];
  static constexpr void inv(const unsigned col[NW], unsigned out[NW]) {
    unsigned rm[NW] = {}, ri[NW] = {};
    for (int r = 0; r < NW; ++r) { rm[r] = 0; ri[r] = 1u << r; }
    for (int b = 0; b < NW; ++b)
      for (int r = 0; r < NW; ++r) rm[r] |= ((col[b] >> r) & 1u) << b;
    for (int c = 0; c < NW; ++c) {
      int piv = c;
      while (!((rm[piv] >> c) & 1u)) ++piv;
      unsigned tm = rm[c]; rm[c] = rm[piv]; rm[piv] = tm;
      unsigned ti = ri[c]; ri[c] = ri[piv]; ri[piv] = ti;
      for (int r = 0; r < NW; ++r)
        if (r != c && ((rm[r] >> c) & 1u)) { rm[r] ^= rm[c]; ri[r] ^= ri[c]; }
    }
    for (int r = 0; r < NW; ++r) out[r] = ri[r];
  }
  constexpr CT() : M{}, S{}, R{} {
    unsigned c1[NW] = {}, c2[NW] = {};
    for (int b = 0; b < NW; ++b) { c1[b] = gperm(1u << b); c2[b] = gperm(c1[b]); }
    unsigned i1[NW] = {}, i2[NW] = {};
    inv(c1, i1); inv(c2, i2);
    for (int w = 0; w < NW; ++w) { M[w] = c1[13 - w]; S[w] = i1[13 - w]; R[w] = i2[13 - w]; }
  }
};
static constexpr CT qct{};
static_assert(qct.M[0] == 0x3000u && qct.M[12] == 0x3u && qct.M[13] == 0x3001u, "mask check");
static_assert(qct.M[4] == 0x300u, "mask check");

// ---------------- complex helpers ----------------
__device__ __forceinline__ float2 cmul(float2 a, float2 b) {
  return make_float2(fmaf(a.x, b.x, -a.y * b.y), fmaf(a.x, b.y, a.y * b.x));
}
__device__ __forceinline__ float2 cmadd(float2 a, float2 b, float2 c) {  // a*b + c
  return make_float2(fmaf(a.x, b.x, fmaf(-a.y, b.y, c.x)),
                     fmaf(a.x, b.y, fmaf(a.y, b.x, c.y)));
}

// fused M = RX(ax) * RZ(az) * RY(ay)
__device__ __forceinline__ void make_mat(float ay, float az, float ax_, float2 m[4]) {
  float c, s, ct, st, cr, sr;
  sincosf(0.5f * ay, &s, &c);
  sincosf(0.5f * az, &st, &ct);
  sincosf(0.5f * ax_, &sr, &cr);
  float2 em = make_float2(ct, -st), ep = make_float2(ct, st);
  float2 r00 = make_float2(c * em.x, c * em.y);
  float2 r01 = make_float2(-s * em.x, -s * em.y);
  float2 r10 = make_float2(s * ep.x, s * ep.y);
  float2 r11 = make_float2(c * ep.x, c * ep.y);
  float2 isr = make_float2(0.f, -sr);
  m[0] = cmadd(isr, r10, make_float2(cr * r00.x, cr * r00.y));
  m[1] = cmadd(isr, r11, make_float2(cr * r01.x, cr * r01.y));
  m[2] = cmadd(isr, r00, make_float2(cr * r10.x, cr * r10.y));
  m[3] = cmadd(isr, r01, make_float2(cr * r11.x, cr * r11.y));
}

// ---------------- DPP lane-xor (lane bits 0..3 only, pure VALU) ----------------
template <int CTRL> __device__ __forceinline__ int dppi(int x) {
  return __builtin_amdgcn_update_dpp(0, x, CTRL, 0xF, 0xF, true);
}
template <unsigned LM> __device__ __forceinline__ float lane_xor1(float x) {
  static_assert(LM < 16u, "lane xor must be within 16-lane row");
  if constexpr (LM == 0u) return x;
  int v = __float_as_int(x);
  if constexpr ((LM & 0xCu) == 0xCu) v = dppi<0x140>(v);       // row_mirror: xor 15
  else if constexpr ((LM & 0xCu) == 0x4u) v = dppi<0x141>(v);  // half_mirror: xor 7
  else if constexpr ((LM & 0xCu) == 0x8u) v = dppi<0x128>(v);  // row_ror:8 : xor 8
  constexpr unsigned REM = ((LM & 0xCu) == 0xCu)   ? (LM ^ 0xFu)
                           : ((LM & 0xCu) == 0x4u) ? (LM ^ 0x7u)
                           : ((LM & 0xCu) == 0x8u) ? (LM ^ 0x8u)
                                                   : LM;
  if constexpr (REM != 0u) {
    constexpr int QC = (int)((0u ^ REM) | ((1u ^ REM) << 2) | ((2u ^ REM) << 4) |
                             ((3u ^ REM) << 6));
    v = dppi<QC>(v);
  }
  return __int_as_float(v);
}
template <unsigned LM> __device__ __forceinline__ float2 lane_xor2(float2 v) {
  if constexpr (LM == 0u) return v;
  return make_float2(lane_xor1<LM>(v.x), lane_xor1<LM>(v.y));
}

// ---------------- generic 8-amp register gate ----------------
// RM: reg-space pair mask; LM: lane-bit(0..3) xor mask; SR: reg-space S bits.
template <unsigned RM, unsigned LM, unsigned SR>
__device__ __forceinline__ void gate8(float2 (&a)[8], const float2* g, bool st_) {
  float2 e00 = g[0], e01 = g[1], e10 = g[2], e11 = g[3];
  float2 f00 = st_ ? e11 : e00, f01 = st_ ? e10 : e01;
  float2 f10 = st_ ? e01 : e10, f11 = st_ ? e00 : e11;
  if constexpr (RM == 0u) {
#pragma unroll
    for (int r = 0; r < 8; ++r) {
      float2 p = lane_xor2<LM>(a[r]);
      if (__builtin_popcount((unsigned)r & SR) & 1)
        a[r] = cmadd(f10, p, cmul(f11, a[r]));
      else
        a[r] = cmadd(f01, p, cmul(f00, a[r]));
    }
  } else {
    constexpr unsigned HB = topbit(RM);
#pragma unroll
    for (int r = 0; r < 8; ++r) {
      if (r & (int)HB) continue;
      const int r2 = r ^ (int)RM;
      float2 A = a[r], B = a[r2];
      float2 pA = lane_xor2<LM>(B), pB = lane_xor2<LM>(A);
      a[r] = (__builtin_popcount((unsigned)r & SR) & 1) ? cmadd(f10, pA, cmul(f11, A))
                                                        : cmadd(f01, pA, cmul(f00, A));
      a[r2] = (__builtin_popcount((unsigned)r2 & SR) & 1) ? cmadd(f10, pB, cmul(f11, B))
                                                          : cmadd(f01, pB, cmul(f00, B));
    }
  }
}

// ================= KERNEL A =================
// block = bat*2 + h, h = q13.  8192 amps/block, 8 amps/thread.
// Phase A1: reg{q0,q1,q2}, lane{q3,q4,q5,q6 | q7,q8}, wave{q9..q12}  (p = t<<3 | r)
// Phase A2: reg{q10,q11,q12}, lane{q6,q7,q8,q9 | q4,q5}, wave{q0..q3}
// Gates A1: w=12..7 (bits 0..6); A2: w=6..1 (bits 6..12).
template <int W>
__device__ __forceinline__ void applyA1(float2 (&a)[8], const float2* g, unsigned qb) {
  constexpr unsigned M = qct.M[W], S = qct.S[W];
  static_assert((M & ~0x7Fu) == 0u, "A1 gate out of window");
  gate8<(M & 7u), ((M >> 3) & 0xFu), (S & 7u)>(a, g, (__popc(qb & S) & 1) != 0);
}
template <int W>
__device__ __forceinline__ void applyA2(float2 (&a)[8], const float2* g, unsigned qb) {
  constexpr unsigned M = qct.M[W], S = qct.S[W];
  static_assert((M & ~0x1FC0u) == 0u, "A2 gate out of window");
  gate8<((M >> 10) & 7u), ((M >> 6) & 0xFu), ((S >> 10) & 7u)>(a, g, (__popc(qb & S) & 1) != 0);
}

__global__ __launch_bounds__(NT) void qsimA(const float* __restrict__ x,
                                            const float* __restrict__ params,
                                            float2* __restrict__ gbuf) {
  __shared__ float2 stx[8192];   // 64 KB exchange
  __shared__ float2 v0[NW][2];
  __shared__ float2 g1m[NW][4];
  __shared__ float2 Ahi[128];
  __shared__ float2 BloP[16][9];  // padded: bank-spread

  const int blk = blockIdx.x;
  const int bat = blk >> 1;
  const unsigned h = (unsigned)blk & 1u;
  const int t = threadIdx.x;

  if (t < NW) {
    float2 m[4];
    make_mat(params[t * 3 + 0] + x[bat * NW + t], params[t * 3 + 1], params[t * 3 + 2], m);
    v0[t][0] = m[0];
    v0[t][1] = m[2];
    make_mat(params[NW * 3 + t * 3 + 0], params[NW * 3 + t * 3 + 1],
             params[NW * 3 + t * 3 + 2], m);
    g1m[t][0] = m[0]; g1m[t][1] = m[1]; g1m[t][2] = m[2]; g1m[t][3] = m[3];
  }
  __syncthreads();
  if (t < 128) {
    float2 pa = make_float2(1.f, 0.f);
#pragma unroll
    for (int w = 0; w < 7; ++w) pa = cmul(pa, v0[w][(t >> (6 - w)) & 1]);
    Ahi[t] = pa;
    float2 pb = make_float2(1.f, 0.f);
#pragma unroll
    for (int w = 7; w < 14; ++w) pb = cmul(pb, v0[w][(t >> (13 - w)) & 1]);
    BloP[t >> 3][t & 7] = pb;
  }
  __syncthreads();

  // init: amp(q) = Ahi[q>>7] * Blo[q&127];  A1: q[12:0] = (t<<3)|r, q13=h
  float2 a[8];
  {
    float2 ahi = Ahi[(((unsigned)t >> 4) & 63u) | (h << 6)];
#pragma unroll
    for (int r = 0; r < 8; ++r) a[r] = cmul(ahi, BloP[t & 15][r]);
  }

  const unsigned qb1 = ((unsigned)t << 3) | (h << 13);  // reg bits zero
  applyA1<12>(a, g1m[12], qb1);   // M=0x03: RM=3
  applyA1<11>(a, g1m[11], qb1);   // M=0x06: RM=6
  applyA1<10>(a, g1m[10], qb1);   // M=0x0C: RM=4, LM=1
  applyA1<9>(a, g1m[9], qb1);     // M=0x18: LM=3
  applyA1<8>(a, g1m[8], qb1);     // M=0x30: LM=6
  applyA1<7>(a, g1m[7], qb1);     // M=0x60: LM=C

  // ---- exchange A1 -> A2 through XOR-swizzled LDS: slot(p) = p ^ ((p>>4)&0xF) ----
  {
    const unsigned g = ((unsigned)t >> 1) & 0xFu, g7 = g & 7u;
    const unsigned gb = ((unsigned)t << 3) ^ (g & 8u);
#pragma unroll
    for (int r = 0; r < 8; ++r) stx[gb | ((unsigned)r ^ g7)] = a[r];
  }
  __syncthreads();
  const unsigned lq = (unsigned)t & 63u, vq = (unsigned)t >> 6;
  // A2 base q (reg bits q10..12 zero): q6..9=lane0..3, q4,5=lane4,5, q0..3=wave
  const unsigned pb = vq | (((lq >> 4) & 3u) << 4) | ((lq & 0xFu) << 6);
  {
    const unsigned rb = pb ^ ((pb >> 4) & 0xFu);
#pragma unroll
    for (int r = 0; r < 8; ++r) a[r] = stx[rb | ((unsigned)r << 10)];
  }

  const unsigned qb2 = pb | (h << 13);
  applyA2<6>(a, g1m[6], qb2);     // M=0x0C0: LM=3
  applyA2<5>(a, g1m[5], qb2);     // M=0x180: LM=6
  applyA2<4>(a, g1m[4], qb2);     // M=0x300: LM=C
  applyA2<3>(a, g1m[3], qb2);     // M=0x600: RM=1, LM=8
  applyA2<2>(a, g1m[2], qb2);     // M=0xC00: RM=3
  applyA2<1>(a, g1m[1], qb2);     // M=0x1800: RM=6

  // ---- store to handoff buffer, A2-natural order: ib = blk<<13 | t<<3 | r ----
  float4* g4 = (float4*)(gbuf + (((size_t)blk) << 13));
  const int b4 = t << 2;
#pragma unroll
  for (int k = 0; k < 4; ++k)
    g4[b4 + k] = make_float4(a[2 * k].x, a[2 * k].y, a[2 * k + 1].x, a[2 * k + 1].y);
}

// ================= KERNEL B =================
// Handoff buffer bit map (within batch): ib0=q10 ib1=q11 ib2=q12 ib3=q6 ib4=q7
// ib5=q8 ib6=q9 ib7=q4 ib8=q5 ib9=q0 ib10=q1 ib11=q2 ib12=q3 ib13=q13.
// B: block = bat*2 + j (j=q3). reg{q0,q12,q13}; lane{q10,q11,q6,q7,q8,q9}; wave{q4,q5,q1,q2}.
__global__ __launch_bounds__(NT) void qsimB(const float* __restrict__ params,
                                            const float2* __restrict__ gbuf,
                                            float* __restrict__ out) {
  __shared__ float2 gA[4], gB[4];
  __shared__ float red[16][NW];

  const int blk = blockIdx.x;
  const int bat = blk >> 1;
  const unsigned j = (unsigned)blk & 1u;  // q3
  const int t = threadIdx.x;

  if (t < 2) {
    const int w = t ? 13 : 0;
    float2 m[4];
    make_mat(params[NW * 3 + w * 3 + 0], params[NW * 3 + w * 3 + 1],
             params[NW * 3 + w * 3 + 2], m);
    float2* g = t ? gB : gA;
    g[0] = m[0]; g[1] = m[1]; g[2] = m[2]; g[3] = m[3];
  }
  __syncthreads();

  const unsigned l = (unsigned)t & 63u, v = (unsigned)t >> 6;
  const unsigned qb = ((l & 1u) << 10) | (((l >> 1) & 1u) << 11) | (((l >> 2) & 1u) << 6) |
                      (((l >> 3) & 1u) << 7) | (((l >> 4) & 1u) << 8) | (((l >> 5) & 1u) << 9) |
                      ((v & 1u) << 4) | (((v >> 1) & 1u) << 5) | (((v >> 2) & 1u) << 1) |
                      (((v >> 3) & 1u) << 2) | (j << 3);
  const unsigned ibb = (l & 1u) | (((l >> 1) & 1u) << 1) | (((l >> 2) & 1u) << 3) |
                       (((l >> 3) & 1u) << 4) | (((l >> 4) & 1u) << 5) | (((l >> 5) & 1u) << 6) |
                       ((v & 1u) << 7) | (((v >> 1) & 1u) << 8) | (((v >> 2) & 1u) << 10) |
                       (((v >> 3) & 1u) << 11) | (j << 12) | ((unsigned)bat << 14);
  float2 a[8];
#pragma unroll
  for (int r = 0; r < 8; ++r)
    a[r] = gbuf[ibb + (((unsigned)r & 1u) << 9) + ((((unsigned)r >> 1) & 1u) << 2) +
                (((unsigned)r >> 2) << 13)];

  // gates w=0 (M bits q12,q13 -> RM=6) and w=13 (M bits q0,q12,q13 -> RM=7)
  {
    constexpr unsigned S0 = qct.S[0];
    constexpr unsigned SR0 = (S0 & 1u) | (((S0 >> 12) & 1u) << 1) | (((S0 >> 13) & 1u) << 2);
    gate8<6u, 0u, SR0>(a, gA, (__popc(qb & S0) & 1) != 0);
    constexpr unsigned S13 = qct.S[13];
    constexpr unsigned SR13 = (S13 & 1u) | (((S13 >> 12) & 1u) << 1) | (((S13 >> 13) & 1u) << 2);
    gate8<7u, 0u, SR13>(a, gB, (__popc(qb & S13) & 1) != 0);
  }

  // measurement: WHT over the 3 reg bits, sign from parity(qb & R)
  float T[8];
#pragma unroll
  for (int r = 0; r < 8; ++r) T[r] = fmaf(a[r].x, a[r].x, a[r].y * a[r].y);
#pragma unroll
  for (int s = 1; s < 8; s <<= 1) {
#pragma unroll
    for (int r = 0; r < 8; ++r) {
      if (!(r & s)) {
        float u = T[r], w_ = T[r ^ s];
        T[r] = u + w_;
        T[r ^ s] = u - w_;
      }
    }
  }

#pragma unroll
  for (int w = 0; w < NW; ++w) {
    constexpr unsigned Rr[NW] = {qct.R[0], qct.R[1], qct.R[2], qct.R[3], qct.R[4],
                                 qct.R[5], qct.R[6], qct.R[7], qct.R[8], qct.R[9],
                                 qct.R[10], qct.R[11], qct.R[12], qct.R[13]};
    const unsigned R = Rr[w];
    const unsigned m = (R & 1u) | (((R >> 12) & 1u) << 1) | (((R >> 13) & 1u) << 2);
    float val = T[m];
    val = (__popc(qb & R) & 1) ? -val : val;
    // wave reduction: DPP for xor1,2,4,8; shfl for 16,32
    val += lane_xor1<1>(val);
    val += lane_xor1<2>(val);
    { float u = lane_xor1<4>(val); val += u; }
    val += lane_xor1<8>(val);
    val += __shfl_xor(val, 16, 64);
    val += __shfl_xor(val, 32, 64);
    if ((t & 63) == 0) red[v][w] = val;
  }
  __syncthreads();
  if (t < NW) {
    float s = 0.f;
#pragma unroll
    for (int i = 0; i < 16; ++i) s += red[i][t];
    atomicAdd(&out[bat * NW + t], s);
  }
}

extern "C" void kernel_launch(void* const* d_in, const int* in_sizes, int n_in,
                              void* d_out, int out_size, void* d_ws, size_t ws_size,
                              hipStream_t stream) {
  (void)in_sizes; (void)n_in; (void)ws_size; (void)out_size;
  const float* x = (const float*)d_in[0];
  const float* params = (const float*)d_in[1];
  float* out = (float*)d_out;
  float2* gbuf = (float2*)d_ws;  // 128*16384 float2 = 16 MB

  hipMemsetAsync(out, 0, BATCH * NW * sizeof(float), stream);
  qsimA<<<dim3(2 * BATCH), dim3(NT), 0, stream>>>(x, params, gbuf);
  qsimB<<<dim3(2 * BATCH), dim3(NT), 0, stream>>>(params, gbuf, out);
}

// Round 4
// 77.057 us; speedup vs baseline: 1.2608x; 1.0100x over previous
//
#include <hip/hip_runtime.h>

#define NW 14
#define NT 1024       // 16 waves
#define BATCH 128

// ---------------- compile-time GF(2) permutation bookkeeping ----------------
constexpr unsigned cnot_pc(unsigned j, int c, int t) {
  int pc = 13 - c, pt = 13 - t;
  return j ^ (((j >> pc) & 1u) << pt);
}
constexpr unsigned gperm(unsigned j) {
  j = cnot_pc(j, 13, 0);
  for (int w = 12; w >= 0; --w) j = cnot_pc(j, w, w + 1);
  return j;
}
constexpr unsigned topbit(unsigned x) {
  unsigned h = 1;
  while (x >>= 1) h <<= 1;
  return h;
}

struct CT {
  unsigned M[NW], S[NW], R[NW];
  static constexpr void inv(const unsigned col[NW], unsigned out[NW]) {
    unsigned rm[NW] = {}, ri[NW] = {};
    for (int r = 0; r < NW; ++r) { rm[r] = 0; ri[r] = 1u << r; }
    for (int b = 0; b < NW; ++b)
      for (int r = 0; r < NW; ++r) rm[r] |= ((col[b] >> r) & 1u) << b;
    for (int c = 0; c < NW; ++c) {
      int piv = c;
      while (!((rm[piv] >> c) & 1u)) ++piv;
      unsigned tm = rm[c]; rm[c] = rm[piv]; rm[piv] = tm;
      unsigned ti = ri[c]; ri[c] = ri[piv]; ri[piv] = ti;
      for (int r = 0; r < NW; ++r)
        if (r != c && ((rm[r] >> c) & 1u)) { rm[r] ^= rm[c]; ri[r] ^= ri[c]; }
    }
    for (int r = 0; r < NW; ++r) out[r] = ri[r];
  }
  constexpr CT() : M{}, S{}, R{} {
    unsigned c1[NW] = {}, c2[NW] = {};
    for (int b = 0; b < NW; ++b) { c1[b] = gperm(1u << b); c2[b] = gperm(c1[b]); }
    unsigned i1[NW] = {}, i2[NW] = {};
    inv(c1, i1); inv(c2, i2);
    for (int w = 0; w < NW; ++w) { M[w] = c1[13 - w]; S[w] = i1[13 - w]; R[w] = i2[13 - w]; }
  }
};
static constexpr CT qct{};
static_assert(qct.M[0] == 0x3000u && qct.M[12] == 0x3u && qct.M[13] == 0x3001u, "mask check");
static_assert(qct.M[4] == 0x300u, "mask check");

// ---------------- complex helpers ----------------
__device__ __forceinline__ float2 cmul(float2 a, float2 b) {
  return make_float2(fmaf(a.x, b.x, -a.y * b.y), fmaf(a.x, b.y, a.y * b.x));
}
__device__ __forceinline__ float2 cmadd(float2 a, float2 b, float2 c) {  // a*b + c
  return make_float2(fmaf(a.x, b.x, fmaf(-a.y, b.y, c.x)),
                     fmaf(a.x, b.y, fmaf(a.y, b.x, c.y)));
}

// fused M = RX(ax) * RZ(az) * RY(ay)
__device__ __forceinline__ void make_mat(float ay, float az, float ax_, float2 m[4]) {
  float c, s, ct, st, cr, sr;
  sincosf(0.5f * ay, &s, &c);
  sincosf(0.5f * az, &st, &ct);
  sincosf(0.5f * ax_, &sr, &cr);
  float2 em = make_float2(ct, -st), ep = make_float2(ct, st);
  float2 r00 = make_float2(c * em.x, c * em.y);
  float2 r01 = make_float2(-s * em.x, -s * em.y);
  float2 r10 = make_float2(s * ep.x, s * ep.y);
  float2 r11 = make_float2(c * ep.x, c * ep.y);
  float2 isr = make_float2(0.f, -sr);
  m[0] = cmadd(isr, r10, make_float2(cr * r00.x, cr * r00.y));
  m[1] = cmadd(isr, r11, make_float2(cr * r01.x, cr * r01.y));
  m[2] = cmadd(isr, r00, make_float2(cr * r10.x, cr * r10.y));
  m[3] = cmadd(isr, r01, make_float2(cr * r11.x, cr * r11.y));
}

// ---------------- DPP lane-xor (lane bits 0..3 only, pure VALU) ----------------
template <int CTRL> __device__ __forceinline__ int dppi(int x) {
  return __builtin_amdgcn_update_dpp(0, x, CTRL, 0xF, 0xF, true);
}
template <unsigned LM> __device__ __forceinline__ float lane_xor1(float x) {
  static_assert(LM < 16u, "lane xor must be within 16-lane row");
  if constexpr (LM == 0u) return x;
  int v = __float_as_int(x);
  if constexpr ((LM & 0xCu) == 0xCu) v = dppi<0x140>(v);       // row_mirror: xor 15
  else if constexpr ((LM & 0xCu) == 0x4u) v = dppi<0x141>(v);  // half_mirror: xor 7
  else if constexpr ((LM & 0xCu) == 0x8u) v = dppi<0x128>(v);  // row_ror:8 : xor 8
  constexpr unsigned REM = ((LM & 0xCu) == 0xCu)   ? (LM ^ 0xFu)
                           : ((LM & 0xCu) == 0x4u) ? (LM ^ 0x7u)
                           : ((LM & 0xCu) == 0x8u) ? (LM ^ 0x8u)
                                                   : LM;
  if constexpr (REM != 0u) {
    constexpr int QC = (int)((0u ^ REM) | ((1u ^ REM) << 2) | ((2u ^ REM) << 4) |
                             ((3u ^ REM) << 6));
    v = dppi<QC>(v);
  }
  return __int_as_float(v);
}
template <unsigned LM> __device__ __forceinline__ float2 lane_xor2(float2 v) {
  if constexpr (LM == 0u) return v;
  return make_float2(lane_xor1<LM>(v.x), lane_xor1<LM>(v.y));
}

// ---------------- generic N-amp register gate ----------------
// RM: reg-space pair mask; LM: lane-bit(0..3) xor mask; SR: reg-space S bits.
template <int N, unsigned RM, unsigned LM, unsigned SR>
__device__ __forceinline__ void gateN(float2 (&a)[N], const float2* g, bool st_) {
  float2 e00 = g[0], e01 = g[1], e10 = g[2], e11 = g[3];
  float2 f00 = st_ ? e11 : e00, f01 = st_ ? e10 : e01;
  float2 f10 = st_ ? e01 : e10, f11 = st_ ? e00 : e11;
  if constexpr (RM == 0u) {
#pragma unroll
    for (int r = 0; r < N; ++r) {
      float2 p = lane_xor2<LM>(a[r]);
      if (__builtin_popcount((unsigned)r & SR) & 1)
        a[r] = cmadd(f10, p, cmul(f11, a[r]));
      else
        a[r] = cmadd(f01, p, cmul(f00, a[r]));
    }
  } else {
    constexpr unsigned HB = topbit(RM);
#pragma unroll
    for (int r = 0; r < N; ++r) {
      if (r & (int)HB) continue;
      const int r2 = r ^ (int)RM;
      float2 A = a[r], B = a[r2];
      float2 pA = lane_xor2<LM>(B), pB = lane_xor2<LM>(A);
      a[r] = (__builtin_popcount((unsigned)r & SR) & 1) ? cmadd(f10, pA, cmul(f11, A))
                                                        : cmadd(f01, pA, cmul(f00, A));
      a[r2] = (__builtin_popcount((unsigned)r2 & SR) & 1) ? cmadd(f10, pB, cmul(f11, B))
                                                          : cmadd(f01, pB, cmul(f00, B));
    }
  }
}

// ================= KERNEL A =================
// block = bat*2 + h, h = q13.  8192 amps/block, 8 amps/thread.
// Phase A1: reg{q0,q1,q2}, lane{q3,q4,q5,q6 | q7,q8}, wave{q9..q12}  (p = t<<3 | r)
// Phase A2: reg{q10,q11,q12}, lane{q6,q7,q8,q9 | q4,q5}, wave{q0..q3}
template <int W>
__device__ __forceinline__ void applyA1(float2 (&a)[8], const float2* g, unsigned qb) {
  constexpr unsigned M = qct.M[W], S = qct.S[W];
  static_assert((M & ~0x7Fu) == 0u, "A1 gate out of window");
  gateN<8, (M & 7u), ((M >> 3) & 0xFu), (S & 7u)>(a, g, (__popc(qb & S) & 1) != 0);
}
template <int W>
__device__ __forceinline__ void applyA2(float2 (&a)[8], const float2* g, unsigned qb) {
  constexpr unsigned M = qct.M[W], S = qct.S[W];
  static_assert((M & ~0x1FC0u) == 0u, "A2 gate out of window");
  gateN<8, ((M >> 10) & 7u), ((M >> 6) & 0xFu), ((S >> 10) & 7u)>(a, g,
                                                                  (__popc(qb & S) & 1) != 0);
}

// __launch_bounds__(1024, 4): 4 waves/EU -> 128-VGPR cap. Without the 2nd arg the
// compiler throttled to 64 VGPRs and SPILLED the register state (R2: 7MB FETCH /
// 14MB WRITE of scratch traffic on a 7KB-I/O kernel). 8 float2 + temps fits in 128.
__global__ __launch_bounds__(NT, 4) void qsimA(const float* __restrict__ x,
                                               const float* __restrict__ params,
                                               float2* __restrict__ gbuf) {
  __shared__ float2 stx[8192];   // 64 KB exchange
  __shared__ float2 v0[NW][2];
  __shared__ float2 g1m[NW][4];
  __shared__ float2 Ahi[128];
  __shared__ float2 BloP[16][9];  // padded: bank-spread

  const int blk = blockIdx.x;
  const int bat = blk >> 1;
  const unsigned h = (unsigned)blk & 1u;
  const int t = threadIdx.x;

  if (t < NW) {
    float2 m[4];
    make_mat(params[t * 3 + 0] + x[bat * NW + t], params[t * 3 + 1], params[t * 3 + 2], m);
    v0[t][0] = m[0];
    v0[t][1] = m[2];
    make_mat(params[NW * 3 + t * 3 + 0], params[NW * 3 + t * 3 + 1],
             params[NW * 3 + t * 3 + 2], m);
    g1m[t][0] = m[0]; g1m[t][1] = m[1]; g1m[t][2] = m[2]; g1m[t][3] = m[3];
  }
  __syncthreads();
  if (t < 128) {
    float2 pa = make_float2(1.f, 0.f);
#pragma unroll
    for (int w = 0; w < 7; ++w) pa = cmul(pa, v0[w][(t >> (6 - w)) & 1]);
    Ahi[t] = pa;
    float2 pb = make_float2(1.f, 0.f);
#pragma unroll
    for (int w = 7; w < 14; ++w) pb = cmul(pb, v0[w][(t >> (13 - w)) & 1]);
    BloP[t >> 3][t & 7] = pb;
  }
  __syncthreads();

  // init: amp(q) = Ahi[q>>7] * Blo[q&127];  A1: q[12:0] = (t<<3)|r, q13=h
  float2 a[8];
  {
    float2 ahi = Ahi[(((unsigned)t >> 4) & 63u) | (h << 6)];
#pragma unroll
    for (int r = 0; r < 8; ++r) a[r] = cmul(ahi, BloP[t & 15][r]);
  }

  const unsigned qb1 = ((unsigned)t << 3) | (h << 13);  // reg bits zero
  applyA1<12>(a, g1m[12], qb1);   // M=0x03: RM=3
  applyA1<11>(a, g1m[11], qb1);   // M=0x06: RM=6
  applyA1<10>(a, g1m[10], qb1);   // M=0x0C: RM=4, LM=1
  applyA1<9>(a, g1m[9], qb1);     // M=0x18: LM=3
  applyA1<8>(a, g1m[8], qb1);     // M=0x30: LM=6
  applyA1<7>(a, g1m[7], qb1);     // M=0x60: LM=C

  // ---- exchange A1 -> A2 through XOR-swizzled LDS: slot(p) = p ^ ((p>>4)&0xF) ----
  {
    const unsigned g = ((unsigned)t >> 1) & 0xFu, g7 = g & 7u;
    const unsigned gb = ((unsigned)t << 3) ^ (g & 8u);
#pragma unroll
    for (int r = 0; r < 8; ++r) stx[gb | ((unsigned)r ^ g7)] = a[r];
  }
  __syncthreads();
  const unsigned lq = (unsigned)t & 63u, vq = (unsigned)t >> 6;
  // A2 base q (reg bits q10..12 zero): q6..9=lane0..3, q4,5=lane4,5, q0..3=wave
  const unsigned pb = vq | (((lq >> 4) & 3u) << 4) | ((lq & 0xFu) << 6);
  {
    const unsigned rb = pb ^ ((pb >> 4) & 0xFu);
#pragma unroll
    for (int r = 0; r < 8; ++r) a[r] = stx[rb | ((unsigned)r << 10)];
  }

  const unsigned qb2 = pb | (h << 13);
  applyA2<6>(a, g1m[6], qb2);     // M=0x0C0: LM=3
  applyA2<5>(a, g1m[5], qb2);     // M=0x180: LM=6
  applyA2<4>(a, g1m[4], qb2);     // M=0x300: LM=C
  applyA2<3>(a, g1m[3], qb2);     // M=0x600: RM=1, LM=8
  applyA2<2>(a, g1m[2], qb2);     // M=0xC00: RM=3
  applyA2<1>(a, g1m[1], qb2);     // M=0x1800: RM=6

  // ---- store to handoff buffer, A2-natural order: ib = blk<<13 | t<<3 | r ----
  float4* g4 = (float4*)(gbuf + (((size_t)blk) << 13));
  const int b4 = t << 2;
#pragma unroll
  for (int k = 0; k < 4; ++k)
    g4[b4 + k] = make_float4(a[2 * k].x, a[2 * k].y, a[2 * k + 1].x, a[2 * k + 1].y);
}

// ================= KERNEL B =================
// Handoff buffer bit map (within batch): ib0=q10 ib1=q11 ib2=q12 ib3=q6 ib4=q7
// ib5=q8 ib6=q9 ib7=q4 ib8=q5 ib9=q0 ib10=q1 ib11=q2 ib12=q3 ib13=q13.
// One block per batch (128 blocks): reg{q0,q12,q13,q3} (16 amps), no atomics/memset.
// lane{q10,q11,q6,q7,q8,q9}; wave{q4,q5,q1,q2}.
__global__ __launch_bounds__(NT, 4) void qsimB(const float* __restrict__ params,
                                               const float2* __restrict__ gbuf,
                                               float* __restrict__ out) {
  __shared__ float2 gA[4], gB[4];
  __shared__ float red[16][NW];

  const int bat = blockIdx.x;
  const int t = threadIdx.x;

  if (t < 2) {
    const int w = t ? 13 : 0;
    float2 m[4];
    make_mat(params[NW * 3 + w * 3 + 0], params[NW * 3 + w * 3 + 1],
             params[NW * 3 + w * 3 + 2], m);
    float2* g = t ? gB : gA;
    g[0] = m[0]; g[1] = m[1]; g[2] = m[2]; g[3] = m[3];
  }
  __syncthreads();

  const unsigned l = (unsigned)t & 63u, v = (unsigned)t >> 6;
  // q bits held by thread (reg bits {q0,q3,q12,q13} = 0 here)
  const unsigned qb = ((l & 1u) << 10) | (((l >> 1) & 1u) << 11) | (((l >> 2) & 1u) << 6) |
                      (((l >> 3) & 1u) << 7) | (((l >> 4) & 1u) << 8) | (((l >> 5) & 1u) << 9) |
                      ((v & 1u) << 4) | (((v >> 1) & 1u) << 5) | (((v >> 2) & 1u) << 1) |
                      (((v >> 3) & 1u) << 2);
  const unsigned ibb = (l & 1u) | (((l >> 1) & 1u) << 1) | (((l >> 2) & 1u) << 3) |
                       (((l >> 3) & 1u) << 4) | (((l >> 4) & 1u) << 5) | (((l >> 5) & 1u) << 6) |
                       ((v & 1u) << 7) | (((v >> 1) & 1u) << 8) | (((v >> 2) & 1u) << 10) |
                       (((v >> 3) & 1u) << 11) | ((unsigned)bat << 14);
  // amp index r: bit0=q0(ib9) bit1=q12(ib2) bit2=q13(ib13) bit3=q3(ib12)
  float2 a[16];
#pragma unroll
  for (int r = 0; r < 16; ++r)
    a[r] = gbuf[ibb + (((unsigned)r & 1u) << 9) + ((((unsigned)r >> 1) & 1u) << 2) +
                ((((unsigned)r >> 2) & 1u) << 13) + ((((unsigned)r >> 3) & 1u) << 12)];

  // gates w=0 (M={q12,q13} -> RM=6) and w=13 (M={q0,q12,q13} -> RM=7)
  {
    constexpr unsigned S0 = qct.S[0];
    constexpr unsigned SR0 = (S0 & 1u) | (((S0 >> 12) & 1u) << 1) | (((S0 >> 13) & 1u) << 2) |
                             (((S0 >> 3) & 1u) << 3);
    gateN<16, 6u, 0u, SR0>(a, gA, (__popc(qb & S0) & 1) != 0);
    constexpr unsigned S13 = qct.S[13];
    constexpr unsigned SR13 = (S13 & 1u) | (((S13 >> 12) & 1u) << 1) |
                              (((S13 >> 13) & 1u) << 2) | (((S13 >> 3) & 1u) << 3);
    gateN<16, 7u, 0u, SR13>(a, gB, (__popc(qb & S13) & 1) != 0);
  }

  // measurement: WHT over the 4 reg bits, sign from parity(qb & R)
  float T[16];
#pragma unroll
  for (int r = 0; r < 16; ++r) T[r] = fmaf(a[r].x, a[r].x, a[r].y * a[r].y);
#pragma unroll
  for (int s = 1; s < 16; s <<= 1) {
#pragma unroll
    for (int r = 0; r < 16; ++r) {
      if (!(r & s)) {
        float u = T[r], w_ = T[r ^ s];
        T[r] = u + w_;
        T[r ^ s] = u - w_;
      }
    }
  }

#pragma unroll
  for (int w = 0; w < NW; ++w) {
    constexpr unsigned Rr[NW] = {qct.R[0], qct.R[1], qct.R[2], qct.R[3], qct.R[4],
                                 qct.R[5], qct.R[6], qct.R[7], qct.R[8], qct.R[9],
                                 qct.R[10], qct.R[11], qct.R[12], qct.R[13]};
    const unsigned R = Rr[w];
    const unsigned m = (R & 1u) | (((R >> 12) & 1u) << 1) | (((R >> 13) & 1u) << 2) |
                       (((R >> 3) & 1u) << 3);
    float val = T[m];
    val = (__popc(qb & R) & 1) ? -val : val;
    // wave reduction: DPP for xor1,2,4,8; shfl for 16,32
    val += lane_xor1<1>(val);
    val += lane_xor1<2>(val);
    { float u = lane_xor1<4>(val); val += u; }
    val += lane_xor1<8>(val);
    val += __shfl_xor(val, 16, 64);
    val += __shfl_xor(val, 32, 64);
    if ((t & 63) == 0) red[v][w] = val;
  }
  __syncthreads();
  if (t < NW) {
    float s = 0.f;
#pragma unroll
    for (int i = 0; i < 16; ++i) s += red[i][t];
    out[bat * NW + t] = s;
  }
}

extern "C" void kernel_launch(void* const* d_in, const int* in_sizes, int n_in,
                              void* d_out, int out_size, void* d_ws, size_t ws_size,
                              hipStream_t stream) {
  (void)in_sizes; (void)n_in; (void)ws_size; (void)out_size;
  const float* x = (const float*)d_in[0];
  const float* params = (const float*)d_in[1];
  float* out = (float*)d_out;
  float2* gbuf = (float2*)d_ws;  // 128*16384 float2 = 16 MB

  qsimA<<<dim3(2 * BATCH), dim3(NT), 0, stream>>>(x, params, gbuf);
  qsimB<<<dim3(BATCH), dim3(NT), 0, stream>>>(params, gbuf, out);
}

// Round 5
// 71.503 us; speedup vs baseline: 1.3588x; 1.0777x over previous
//
#include <hip/hip_runtime.h>

#define NW 14
#define NT 1024       // 16 waves
#define BATCH 128

// ---------------- compile-time GF(2) permutation bookkeeping ----------------
constexpr unsigned cnot_pc(unsigned j, int c, int t) {
  int pc = 13 - c, pt = 13 - t;
  return j ^ (((j >> pc) & 1u) << pt);
}
constexpr unsigned gperm(unsigned j) {
  j = cnot_pc(j, 13, 0);
  for (int w = 12; w >= 0; --w) j = cnot_pc(j, w, w + 1);
  return j;
}
constexpr unsigned topbit(unsigned x) {
  unsigned h = 1;
  while (x >>= 1) h <<= 1;
  return h;
}

struct CT {
  unsigned M[NW], S[NW], R[NW];
  static constexpr void inv(const unsigned col[NW], unsigned out[NW]) {
    unsigned rm[NW] = {}, ri[NW] = {};
    for (int r = 0; r < NW; ++r) { rm[r] = 0; ri[r] = 1u << r; }
    for (int b = 0; b < NW; ++b)
      for (int r = 0; r < NW; ++r) rm[r] |= ((col[b] >> r) & 1u) << b;
    for (int c = 0; c < NW; ++c) {
      int piv = c;
      while (!((rm[piv] >> c) & 1u)) ++piv;
      unsigned tm = rm[c]; rm[c] = rm[piv]; rm[piv] = tm;
      unsigned ti = ri[c]; ri[c] = ri[piv]; ri[piv] = ti;
      for (int r = 0; r < NW; ++r)
        if (r != c && ((rm[r] >> c) & 1u)) { rm[r] ^= rm[c]; ri[r] ^= ri[c]; }
    }
    for (int r = 0; r < NW; ++r) out[r] = ri[r];
  }
  constexpr CT() : M{}, S{}, R{} {
    unsigned c1[NW] = {}, c2[NW] = {};
    for (int b = 0; b < NW; ++b) { c1[b] = gperm(1u << b); c2[b] = gperm(c1[b]); }
    unsigned i1[NW] = {}, i2[NW] = {};
    inv(c1, i1); inv(c2, i2);
    for (int w = 0; w < NW; ++w) { M[w] = c1[13 - w]; S[w] = i1[13 - w]; R[w] = i2[13 - w]; }
  }
};
static constexpr CT qct{};
static_assert(qct.M[0] == 0x3000u && qct.M[12] == 0x3u && qct.M[13] == 0x3001u, "mask check");
static_assert(qct.M[4] == 0x300u, "mask check");

// ---------------- complex helpers ----------------
__device__ __forceinline__ float2 cmul(float2 a, float2 b) {
  return make_float2(fmaf(a.x, b.x, -a.y * b.y), fmaf(a.x, b.y, a.y * b.x));
}
__device__ __forceinline__ float2 cmadd(float2 a, float2 b, float2 c) {  // a*b + c
  return make_float2(fmaf(a.x, b.x, fmaf(-a.y, b.y, c.x)),
                     fmaf(a.x, b.y, fmaf(a.y, b.x, c.y)));
}

// fused M = RX(ax) * RZ(az) * RY(ay)
__device__ __forceinline__ void make_mat(float ay, float az, float ax_, float2 m[4]) {
  float c, s, ct, st, cr, sr;
  sincosf(0.5f * ay, &s, &c);
  sincosf(0.5f * az, &st, &ct);
  sincosf(0.5f * ax_, &sr, &cr);
  float2 em = make_float2(ct, -st), ep = make_float2(ct, st);
  float2 r00 = make_float2(c * em.x, c * em.y);
  float2 r01 = make_float2(-s * em.x, -s * em.y);
  float2 r10 = make_float2(s * ep.x, s * ep.y);
  float2 r11 = make_float2(c * ep.x, c * ep.y);
  float2 isr = make_float2(0.f, -sr);
  m[0] = cmadd(isr, r10, make_float2(cr * r00.x, cr * r00.y));
  m[1] = cmadd(isr, r11, make_float2(cr * r01.x, cr * r01.y));
  m[2] = cmadd(isr, r00, make_float2(cr * r10.x, cr * r10.y));
  m[3] = cmadd(isr, r01, make_float2(cr * r11.x, cr * r11.y));
}

// ---------------- lane-xor: DPP for bits 0..3, shfl for bits 4,5 ----------------
template <int CTRL> __device__ __forceinline__ int dppi(int x) {
  return __builtin_amdgcn_update_dpp(0, x, CTRL, 0xF, 0xF, true);
}
template <unsigned LM> __device__ __forceinline__ float lane_xor1(float x) {
  if constexpr (LM == 0u) return x;
  else if constexpr (LM >= 16u) {
    return __shfl_xor(x, (int)LM, 64);
  } else {
    int v = __float_as_int(x);
    if constexpr ((LM & 0xCu) == 0xCu) v = dppi<0x140>(v);       // row_mirror: xor 15
    else if constexpr ((LM & 0xCu) == 0x4u) v = dppi<0x141>(v);  // half_mirror: xor 7
    else if constexpr ((LM & 0xCu) == 0x8u) v = dppi<0x128>(v);  // row_ror:8 : xor 8
    constexpr unsigned REM = ((LM & 0xCu) == 0xCu)   ? (LM ^ 0xFu)
                             : ((LM & 0xCu) == 0x4u) ? (LM ^ 0x7u)
                             : ((LM & 0xCu) == 0x8u) ? (LM ^ 0x8u)
                                                     : LM;
    if constexpr (REM != 0u) {
      constexpr int QC = (int)((0u ^ REM) | ((1u ^ REM) << 2) | ((2u ^ REM) << 4) |
                               ((3u ^ REM) << 6));
      v = dppi<QC>(v);
    }
    return __int_as_float(v);
  }
}
template <unsigned LM> __device__ __forceinline__ float2 lane_xor2(float2 v) {
  if constexpr (LM == 0u) return v;
  return make_float2(lane_xor1<LM>(v.x), lane_xor1<LM>(v.y));
}

// ---------------- generic 16-amp register gate ----------------
// RM: reg-space pair mask; LM: lane xor mask; SR: reg-space S bits.
template <unsigned RM, unsigned LM, unsigned SR>
__device__ __forceinline__ void gate16(float2 (&a)[16], const float2* g, bool st_) {
  float2 e00 = g[0], e01 = g[1], e10 = g[2], e11 = g[3];
  float2 f00 = st_ ? e11 : e00, f01 = st_ ? e10 : e01;
  float2 f10 = st_ ? e01 : e10, f11 = st_ ? e00 : e11;
  if constexpr (RM == 0u) {
#pragma unroll
    for (int r = 0; r < 16; ++r) {
      float2 p = lane_xor2<LM>(a[r]);
      if (__builtin_popcount((unsigned)r & SR) & 1)
        a[r] = cmadd(f10, p, cmul(f11, a[r]));
      else
        a[r] = cmadd(f01, p, cmul(f00, a[r]));
    }
  } else {
    constexpr unsigned HB = topbit(RM);
#pragma unroll
    for (int r = 0; r < 16; ++r) {
      if (r & (int)HB) continue;
      const int r2 = r ^ (int)RM;
      float2 A = a[r], B = a[r2];
      float2 pA = lane_xor2<LM>(B), pB = lane_xor2<LM>(A);
      a[r] = (__builtin_popcount((unsigned)r & SR) & 1) ? cmadd(f10, pA, cmul(f11, A))
                                                        : cmadd(f01, pA, cmul(f00, A));
      a[r2] = (__builtin_popcount((unsigned)r2 & SR) & 1) ? cmadd(f10, pB, cmul(f11, B))
                                                          : cmadd(f01, pB, cmul(f00, B));
    }
  }
}

// ================= SINGLE KERNEL =================
// One block per batch element; 16384 amps in registers (16 float2/thread).
// Phase 1 layout: q = wv<<10 | ln<<4 | r   (reg=q0..3, lane=q4..9, wave=q10..13)
//   gates w=12..4 (M within bits 0..9); w=5 -> shfl xor24, w=4 -> shfl xor48.
// Phase 2 layout: q = r<<10 | qb2          (reg=q10..13, lane0=q0, lane1=q9,
//   lane2..5=q1..4, wave=q5..8); gates w=3,2,1,0,13 all reg/DPP-local.
template <int W>
__device__ __forceinline__ void applyP1(float2 (&a)[16], const float2* g, unsigned qb) {
  constexpr unsigned M = qct.M[W], S = qct.S[W];
  static_assert((M & ~0x3FFu) == 0u, "P1 gate out of window");
  gate16<(M & 0xFu), ((M >> 4) & 0x3Fu), (S & 0xFu)>(a, g, (__popc(qb & S) & 1) != 0);
}
template <int W>
__device__ __forceinline__ void applyP2(float2 (&a)[16], const float2* g, unsigned qb) {
  constexpr unsigned M = qct.M[W], S = qct.S[W];
  static_assert((M & ~0x3E01u) == 0u, "P2 gate out of window");
  gate16<((M >> 10) & 0xFu), ((M & 1u) | (((M >> 9) & 1u) << 1)), ((S >> 10) & 0xFu)>(
      a, g, (__popc(qb & S) & 1) != 0);
}

// launch_bounds(1024,4): 4 waves/EU -> 128-VGPR cap; a[16]=32 VGPR state + temps
// fits without spill (R2's 64-VGPR default spilled 7MB/14MB to scratch).
__global__ __launch_bounds__(NT, 4) void qsim(const float* __restrict__ x,
                                              const float* __restrict__ params,
                                              float* __restrict__ out) {
  __shared__ float2 stx[16384];   // 128 KB transpose buffer
  __shared__ float2 v0[NW][2];
  __shared__ float2 g1m[NW][4];
  __shared__ float2 Ahi[128];
  __shared__ float2 BloP[8][17];  // padded rows: conflict-spread
  __shared__ float red[16][NW];

  const int bat = blockIdx.x;
  const int t = threadIdx.x;
  const unsigned ln = (unsigned)t & 63u, wv = (unsigned)t >> 6;

  if (t < NW) {
    float2 m[4];
    make_mat(params[t * 3 + 0] + x[bat * NW + t], params[t * 3 + 1], params[t * 3 + 2], m);
    v0[t][0] = m[0];
    v0[t][1] = m[2];
    make_mat(params[NW * 3 + t * 3 + 0], params[NW * 3 + t * 3 + 1],
             params[NW * 3 + t * 3 + 2], m);
    g1m[t][0] = m[0]; g1m[t][1] = m[1]; g1m[t][2] = m[2]; g1m[t][3] = m[3];
  }
  __syncthreads();
  if (t < 128) {
    float2 pa = make_float2(1.f, 0.f);
#pragma unroll
    for (int w = 0; w < 7; ++w) pa = cmul(pa, v0[w][(t >> (6 - w)) & 1]);
    Ahi[t] = pa;
    float2 pb = make_float2(1.f, 0.f);
#pragma unroll
    for (int w = 7; w < 14; ++w) pb = cmul(pb, v0[w][(t >> (13 - w)) & 1]);
    BloP[t >> 4][t & 15] = pb;   // index j = q&127: row j>>4 = q6..4, col j&15 = q3..0
  }
  __syncthreads();

  // ---- init: amp(q) = Ahi[q>>7] * Blo[q&127]; q>>7 = wv<<3 | ln>>3 (thread-uniform)
  float2 a[16];
  {
    float2 ahi = Ahi[(wv << 3) | (ln >> 3)];
#pragma unroll
    for (int r = 0; r < 16; ++r) a[r] = cmul(ahi, BloP[ln & 7][r]);
  }

  // ---- phase-1 gates ----
  const unsigned qb1 = (ln << 4) | (wv << 10);
  applyP1<12>(a, g1m[12], qb1);  // RM=3
  applyP1<11>(a, g1m[11], qb1);  // RM=6
  applyP1<10>(a, g1m[10], qb1);  // RM=12
  applyP1<9>(a, g1m[9], qb1);    // RM=8, LM=1 (DPP)
  applyP1<8>(a, g1m[8], qb1);    // LM=3  (DPP)
  applyP1<7>(a, g1m[7], qb1);    // LM=6  (DPP)
  applyP1<6>(a, g1m[6], qb1);    // LM=12 (DPP)
  applyP1<5>(a, g1m[5], qb1);    // LM=24 (shfl)
  applyP1<4>(a, g1m[4], qb1);    // LM=48 (shfl)

  // ---- transpose through XOR-swizzled LDS: slot(q) = q ^ ((q>>4)&0xF) ----
  // write: slot = (wv<<10 | ln<<4 | (ln&0xF)) ^ r    (b64, 4 lanes/bank = floor)
  {
    const unsigned bw = (wv << 10) | (ln << 4) | (ln & 0xFu);
#pragma unroll
    for (int r = 0; r < 16; ++r) stx[bw ^ (unsigned)r] = a[r];
  }
  __syncthreads();
  // phase-2 thread bits (reg q10..13 = 0):
  const unsigned qb2 = (ln & 1u) | (((ln >> 2) & 0xFu) << 1) | (wv << 5) |
                       (((ln >> 1) & 1u) << 9);
  {
    const unsigned c2 = ((ln >> 5) & 1u) | ((wv & 7u) << 1);
    const unsigned br = qb2 ^ c2;
#pragma unroll
    for (int r = 0; r < 16; ++r) a[r] = stx[br | ((unsigned)r << 10)];
  }

  // ---- phase-2 gates ----
  applyP2<3>(a, g1m[3], qb2);    // RM=1, LM=2 (DPP)
  applyP2<2>(a, g1m[2], qb2);    // RM=3
  applyP2<1>(a, g1m[1], qb2);    // RM=6
  applyP2<0>(a, g1m[0], qb2);    // RM=12
  applyP2<13>(a, g1m[13], qb2);  // RM=12, LM=1 (DPP)

  // ---- measurement: WHT over the 4 reg bits (q10..13), sign from parity(qb2&R) ----
  float T[16];
#pragma unroll
  for (int r = 0; r < 16; ++r) T[r] = fmaf(a[r].x, a[r].x, a[r].y * a[r].y);
#pragma unroll
  for (int s = 1; s < 16; s <<= 1) {
#pragma unroll
    for (int r = 0; r < 16; ++r) {
      if (!(r & s)) {
        float u = T[r], v = T[r ^ s];
        T[r] = u + v;
        T[r ^ s] = u - v;
      }
    }
  }

#pragma unroll
  for (int w = 0; w < NW; ++w) {
    constexpr unsigned Rr[NW] = {qct.R[0], qct.R[1], qct.R[2], qct.R[3], qct.R[4],
                                 qct.R[5], qct.R[6], qct.R[7], qct.R[8], qct.R[9],
                                 qct.R[10], qct.R[11], qct.R[12], qct.R[13]};
    const unsigned R = Rr[w];
    float val = T[(R >> 10) & 0xFu];
    val = (__popc(qb2 & R) & 1) ? -val : val;
    val += lane_xor1<1>(val);
    val += lane_xor1<2>(val);
    { float u = lane_xor1<4>(val); val += u; }
    val += lane_xor1<8>(val);
    val += __shfl_xor(val, 16, 64);
    val += __shfl_xor(val, 32, 64);
    if ((t & 63) == 0) red[wv][w] = val;
  }
  __syncthreads();
  if (t < NW) {
    float s = 0.f;
#pragma unroll
    for (int i = 0; i < 16; ++i) s += red[i][t];
    out[bat * NW + t] = s;
  }
}

extern "C" void kernel_launch(void* const* d_in, const int* in_sizes, int n_in,
                              void* d_out, int out_size, void* d_ws, size_t ws_size,
                              hipStream_t stream) {
  (void)in_sizes; (void)n_in; (void)d_ws; (void)ws_size; (void)out_size;
  const float* x = (const float*)d_in[0];
  const float* params = (const float*)d_in[1];
  float* out = (float*)d_out;
  qsim<<<dim3(BATCH), dim3(NT), 0, stream>>>(x, params, out);
}